// Round 5
// baseline (107.666 us; speedup 1.0000x reference)
//
#include <hip/hip_runtime.h>
#include <hip/hip_bf16.h>
#include <math.h>

// Problem constants
#define BS 8
#define NQ 4096
#define E  256
#define NH 8
#define NP 4
#define HD 32
#define GW 64
#define GH 64
#define T  (BS * NQ)     // 32768
#define NPAD 384
#define MSTR 96          // meta row: 64 offsets + 32 logits (bf16)

typedef __attribute__((ext_vector_type(8))) short bf16x8;
typedef __attribute__((ext_vector_type(4))) float f32x4;
typedef __attribute__((ext_vector_type(8))) unsigned short u16x8;

__device__ __forceinline__ float b2f(unsigned short u) {
    union { unsigned int i; float f; } x; x.i = ((unsigned int)u) << 16; return x.f;
}
__device__ __forceinline__ unsigned short f2b(float f) {
    __hip_bfloat16 h = __float2bfloat16(f);
    return *reinterpret_cast<unsigned short*>(&h);
}
__device__ __forceinline__ void gload16(const void* g, void* l) {
    __builtin_amdgcn_global_load_lds(
        (__attribute__((address_space(1))) void*)g,
        (__attribute__((address_space(3))) void*)l, 16, 0, 0);
}

// ---------------------------------------------------------------------------
// prep: Wcat (NPAD x 256 bf16), Wo (256x256 bf16), bcat (fp32 NPAD)
// ---------------------------------------------------------------------------
__global__ __launch_bounds__(256) void prep_weights(
    const float* __restrict__ vw, const float* __restrict__ vb,
    const float* __restrict__ ow, const float* __restrict__ ob,
    const float* __restrict__ aw, const float* __restrict__ ab,
    const float* __restrict__ outw,
    unsigned short* __restrict__ Wcat, unsigned short* __restrict__ Wo,
    float* __restrict__ bcat)
{
    int i = blockIdx.x * 256 + threadIdx.x;
    if (i < NPAD * E) {
        int n = i >> 8, k = i & 255;
        float w = 0.f;
        if      (n < 256) w = vw[n * E + k];
        else if (n < 320) w = ow[(n - 256) * E + k];
        else if (n < 352) w = aw[(n - 320) * E + k];
        Wcat[i] = f2b(w);
    } else {
        int j = i - NPAD * E;
        if (j < E * E) Wo[j] = f2b(outw[j]);
    }
    if (i < NPAD) {
        float bv = 0.f;
        if      (i < 256) bv = vb[i];
        else if (i < 320) bv = ob[i - 256];
        else if (i < 352) bv = ab[i - 320];
        bcat[i] = bv;
    }
}

// ---------------------------------------------------------------------------
// GEMM1 (projection): 32 rows x 384 cols per block; grid 1024 blocks.
// Query read exactly once. 4 waves; wave w: 32 rows (2 m-frags) x 96 cols
// (6 n-frags). A: fp32 -> bf16 regs -> LDS (128 granules). B: gload_lds
// (1536 granules). Epilogue scatters to Vt (value, image layout) + Mt (meta).
// ---------------------------------------------------------------------------
__global__ __launch_bounds__(256) void gemm_proj(
    const float* __restrict__ Aq,
    const unsigned short* __restrict__ W,
    const float* __restrict__ bias,
    unsigned short* __restrict__ Vt,
    unsigned short* __restrict__ Mt)
{
    // shorts: A granules [0,1024), B granules [1024, 1024+12288)
    __shared__ __align__(16) unsigned short lds[1024 + 12288];

    const int tid  = threadIdx.x;
    const int lane = tid & 63;
    const int wave = tid >> 6;
    const int bm = blockIdx.x * 32;
    const int cb = wave * 96;
    const int lrow   = lane & 15;
    const int lchunk = lane >> 4;
    const int K = 256;

    f32x4 acc[2][6] = {};

    for (int k0 = 0; k0 < K; k0 += 32) {
        // B: 1536 granules, 6 per thread (dest = wave-uniform + lane*16)
#pragma unroll
        for (int p = 0; p < 6; ++p) {
            int g = p * 256 + wave * 64 + lane;
            int row = g % 384, chunk = g / 384;
            gload16(W + (size_t)row * K + k0 + chunk * 8,
                    &lds[1024 + (size_t)g * 8]);
        }
        // A: 128 granules, threads 0..127
        if (tid < 128) {
            int arow = tid & 31, achunk = tid >> 5;
            const float* ap = Aq + (size_t)(bm + arow) * K + k0 + achunk * 8;
            float4 f0 = *(const float4*)(ap + 0);
            float4 f1 = *(const float4*)(ap + 4);
            u16x8 g0;
            g0[0]=f2b(f0.x); g0[1]=f2b(f0.y); g0[2]=f2b(f0.z); g0[3]=f2b(f0.w);
            g0[4]=f2b(f1.x); g0[5]=f2b(f1.y); g0[6]=f2b(f1.z); g0[7]=f2b(f1.w);
            *(u16x8*)&lds[(size_t)(achunk * 32 + arow) * 8] = g0;
        }
        __syncthreads();

        bf16x8 af[2], bfr[6];
#pragma unroll
        for (int m = 0; m < 2; ++m)
            af[m] = *(const bf16x8*)&lds[(size_t)(lchunk * 32 + m * 16 + lrow) * 8];
#pragma unroll
        for (int n = 0; n < 6; ++n)
            bfr[n] = *(const bf16x8*)&lds[1024 + (size_t)(lchunk * 384 + cb + n * 16 + lrow) * 8];

#pragma unroll
        for (int m = 0; m < 2; ++m)
#pragma unroll
            for (int n = 0; n < 6; ++n)
                acc[m][n] = __builtin_amdgcn_mfma_f32_16x16x32_bf16(
                    af[m], bfr[n], acc[m][n], 0, 0, 0);
        __syncthreads();
    }

    const int orow0 = (lane >> 4) * 4;
    const int ocol  = lane & 15;
#pragma unroll
    for (int n = 0; n < 6; ++n) {
        int colg = cb + n * 16 + ocol;
        if (colg >= 352) continue;
        float bv = bias[colg];
#pragma unroll
        for (int m = 0; m < 2; ++m) {
#pragma unroll
            for (int r = 0; r < 4; ++r) {
                int rowg = bm + m * 16 + orow0 + r;
                unsigned short v = f2b(acc[m][n][r] + bv);
                if (colg < 256) {
                    int b = rowg >> 12, q = rowg & 4095;
                    int h = colg >> 5, ch = colg & 31;
                    Vt[((size_t)(((b << 3) + h) << 12) + q) * 32 + ch] = v;
                } else if (colg < 320) {
                    Mt[(size_t)rowg * MSTR + (colg - 256)] = v;
                } else {
                    Mt[(size_t)rowg * MSTR + 64 + (colg - 320)] = v;
                }
            }
        }
    }
}

// ---------------------------------------------------------------------------
// Sampling: thread per (t, h, 8-ch group); 4096 blocks, XCD-swizzled so each
// XCD's L2 holds one batch image (2 MB). Branchless: clamped indices +
// validity-zeroed weights (identical to reference clip+mask semantics).
// ---------------------------------------------------------------------------
__global__ __launch_bounds__(256) void sample_kernel(
    const unsigned short* __restrict__ Vt,
    const unsigned short* __restrict__ Mt,
    unsigned short* __restrict__ S)
{
    const int blk = ((blockIdx.x & 7) << 9) + (blockIdx.x >> 3);  // 4096 = 8*512
    const int gid = blk * 256 + threadIdx.x;
    const int d0 = gid & 3;
    const int h  = (gid >> 2) & 7;
    const int t  = gid >> 5;
    const int b  = t >> 12;
    const int q  = t & 4095;

    const float refx = (float)(q & 63) * (64.0f / 63.0f);
    const float refy = (float)(q >> 6) * (64.0f / 63.0f);

    const unsigned short* __restrict__ mrow = Mt + (size_t)t * MSTR;
    u16x8  offv = *(const u16x8*)&mrow[h * 8];
    ushort4 lg  = *(const ushort4*)&mrow[64 + h * 4];

    float l0 = b2f(lg.x), l1 = b2f(lg.y), l2 = b2f(lg.z), l3 = b2f(lg.w);
    float m = fmaxf(fmaxf(l0, l1), fmaxf(l2, l3));
    float e0 = __expf(l0 - m), e1 = __expf(l1 - m);
    float e2 = __expf(l2 - m), e3 = __expf(l3 - m);
    float inv = 1.0f / (e0 + e1 + e2 + e3);
    float at[4] = {e0 * inv, e1 * inv, e2 * inv, e3 * inv};

    const unsigned short* __restrict__ vbase =
        Vt + ((size_t)(((b << 3) + h) << 12)) * 32 + d0 * 8;

    float acc[8] = {};
#pragma unroll
    for (int p = 0; p < NP; ++p) {
        float ox = b2f(offv[2 * p]);
        float oy = b2f(offv[2 * p + 1]);
        float px = refx + ox - 0.5f;
        float py = refy + oy - 0.5f;
        float fx = floorf(px), fy = floorf(py);
        int x0 = (int)fx, y0 = (int)fy;
        float wx = px - fx, wy = py - fy;
        float a = at[p];

        int x1 = x0 + 1, y1 = y0 + 1;
        float vx0 = (x0 >= 0 && x0 < GW) ? 1.f : 0.f;
        float vx1 = (x1 >= 0 && x1 < GW) ? 1.f : 0.f;
        float vy0 = (y0 >= 0 && y0 < GH) ? 1.f : 0.f;
        float vy1 = (y1 >= 0 && y1 < GH) ? 1.f : 0.f;

        float w00 = (1.f - wx) * (1.f - wy) * a * vx0 * vy0;
        float w10 = wx * (1.f - wy) * a * vx1 * vy0;
        float w01 = (1.f - wx) * wy * a * vx0 * vy1;
        float w11 = wx * wy * a * vx1 * vy1;

        int x0c = min(max(x0, 0), GW - 1), x1c = min(max(x1, 0), GW - 1);
        int y0c = min(max(y0, 0), GH - 1), y1c = min(max(y1, 0), GH - 1);

        u16x8 g00 = *(const u16x8*)&vbase[(size_t)(y0c * GW + x0c) * 32];
        u16x8 g10 = *(const u16x8*)&vbase[(size_t)(y0c * GW + x1c) * 32];
        u16x8 g01 = *(const u16x8*)&vbase[(size_t)(y1c * GW + x0c) * 32];
        u16x8 g11 = *(const u16x8*)&vbase[(size_t)(y1c * GW + x1c) * 32];
#pragma unroll
        for (int j = 0; j < 8; ++j)
            acc[j] += w00 * b2f(g00[j]) + w10 * b2f(g10[j])
                    + w01 * b2f(g01[j]) + w11 * b2f(g11[j]);
    }

    u16x8 o;
#pragma unroll
    for (int j = 0; j < 8; ++j) o[j] = f2b(acc[j]);
    *(u16x8*)&S[(size_t)t * E + h * HD + d0 * 8] = o;
}

// ---------------------------------------------------------------------------
// GEMM2 (output projection): 32 rows x 256 cols per block; grid 1024.
// S (T x 256 bf16) @ Wo^T + out_b + 2*query; fp32 out.
// ---------------------------------------------------------------------------
__global__ __launch_bounds__(256) void gemm_out(
    const unsigned short* __restrict__ A,
    const unsigned short* __restrict__ W,
    const float* __restrict__ bias,
    const float* __restrict__ resid,
    float* __restrict__ Out)
{
    // shorts: A granules [0,1024), B granules [1024, 1024+8192)
    __shared__ __align__(16) unsigned short smem[1024 + 8192];

    const int tid  = threadIdx.x;
    const int lane = tid & 63;
    const int wave = tid >> 6;
    const int bm = blockIdx.x * 32;
    const int cb = wave * 64;
    const int lrow   = lane & 15;
    const int lchunk = lane >> 4;
    const int K = 256;

    f32x4 acc[2][4] = {};

    for (int k0 = 0; k0 < K; k0 += 32) {
        if (wave < 2) {  // A: 128 granules
            int g = wave * 64 + lane;
            int row = g & 31, chunk = g >> 5;
            gload16(A + (size_t)(bm + row) * K + k0 + chunk * 8,
                    &smem[(size_t)g * 8]);
        }
#pragma unroll
        for (int p = 0; p < 4; ++p) {  // B: 1024 granules
            int g = p * 256 + wave * 64 + lane;
            int row = g & 255, chunk = g >> 8;
            gload16(W + (size_t)row * K + k0 + chunk * 8,
                    &smem[1024 + (size_t)g * 8]);
        }
        __syncthreads();

        bf16x8 af[2], bfr[4];
#pragma unroll
        for (int m = 0; m < 2; ++m)
            af[m] = *(const bf16x8*)&smem[(size_t)(lchunk * 32 + m * 16 + lrow) * 8];
#pragma unroll
        for (int n = 0; n < 4; ++n)
            bfr[n] = *(const bf16x8*)&smem[1024 + (size_t)(lchunk * 256 + cb + n * 16 + lrow) * 8];

#pragma unroll
        for (int m = 0; m < 2; ++m)
#pragma unroll
            for (int n = 0; n < 4; ++n)
                acc[m][n] = __builtin_amdgcn_mfma_f32_16x16x32_bf16(
                    af[m], bfr[n], acc[m][n], 0, 0, 0);
        __syncthreads();
    }

    const int orow0 = (lane >> 4) * 4;
    const int ocol  = lane & 15;
#pragma unroll
    for (int m = 0; m < 2; ++m) {
#pragma unroll
        for (int n = 0; n < 4; ++n) {
            int colg = cb + n * 16 + ocol;
            float bv = bias[colg];
#pragma unroll
            for (int r = 0; r < 4; ++r) {
                int rowg = bm + m * 16 + orow0 + r;
                Out[(size_t)rowg * 256 + colg] =
                    acc[m][n][r] + bv + 2.0f * resid[(size_t)rowg * 256 + colg];
            }
        }
    }
}

// ---------------------------------------------------------------------------
extern "C" void kernel_launch(void* const* d_in, const int* in_sizes, int n_in,
                              void* d_out, int out_size, void* d_ws, size_t ws_size,
                              hipStream_t stream)
{
    const float* query   = (const float*)d_in[0];
    const float* value_w = (const float*)d_in[1];
    const float* value_b = (const float*)d_in[2];
    const float* off_w   = (const float*)d_in[3];
    const float* off_b   = (const float*)d_in[4];
    const float* attn_w  = (const float*)d_in[5];
    const float* attn_b  = (const float*)d_in[6];
    const float* out_w   = (const float*)d_in[7];
    const float* out_b   = (const float*)d_in[8];

    char* w = (char*)d_ws;
    unsigned short* Vt   = (unsigned short*)w;  w += (size_t)T * E * 2;      // 16 MB
    unsigned short* Mt   = (unsigned short*)w;  w += (size_t)T * MSTR * 2;   // 6 MB
    unsigned short* S    = (unsigned short*)w;  w += (size_t)T * E * 2;      // 16 MB
    unsigned short* Wcat = (unsigned short*)w;  w += (size_t)NPAD * E * 2;
    unsigned short* Wo   = (unsigned short*)w;  w += (size_t)E * E * 2;
    float*          bcat = (float*)w;

    prep_weights<<<(NPAD * E + E * E + 255) / 256, 256, 0, stream>>>(
        value_w, value_b, off_w, off_b, attn_w, attn_b, out_w, Wcat, Wo, bcat);

    gemm_proj<<<T / 32, 256, 0, stream>>>(query, Wcat, bcat, Vt, Mt);

    sample_kernel<<<T * 32 / 256, 256, 0, stream>>>(Vt, Mt, S);

    gemm_out<<<T / 32, 256, 0, stream>>>(S, Wo, out_b, query, (float*)d_out);
}

// Round 6
// 86.046 us; speedup vs baseline: 1.2513x; 1.2513x over previous
//
#include <hip/hip_runtime.h>
#include <hip/hip_bf16.h>
#include <math.h>

// Problem constants
#define BS 8
#define NQ 4096
#define E  256
#define NH 8
#define NP 4
#define HD 32
#define GW 64
#define GH 64
#define T  (BS * NQ)     // 32768
#define NPAD 384
#define MSTR 96          // meta row: 64 offsets + 32 logits (bf16)

typedef __attribute__((ext_vector_type(8))) short bf16x8;
typedef __attribute__((ext_vector_type(4))) float f32x4;
typedef __attribute__((ext_vector_type(8))) unsigned short u16x8;

__device__ __forceinline__ float b2f(unsigned short u) {
    union { unsigned int i; float f; } x; x.i = ((unsigned int)u) << 16; return x.f;
}
__device__ __forceinline__ unsigned short f2b(float f) {
    __hip_bfloat16 h = __float2bfloat16(f);
    return *reinterpret_cast<unsigned short*>(&h);
}
__device__ __forceinline__ void gload16(const void* g, void* l) {
    __builtin_amdgcn_global_load_lds(
        (__attribute__((address_space(1))) void*)g,
        (__attribute__((address_space(3))) void*)l, 16, 0, 0);
}

// ---------------------------------------------------------------------------
// prep: Wcat (NPAD x 256 bf16), Wo (256x256 bf16), bcat (fp32 NPAD)
// ---------------------------------------------------------------------------
__global__ __launch_bounds__(256) void prep_weights(
    const float* __restrict__ vw, const float* __restrict__ vb,
    const float* __restrict__ ow, const float* __restrict__ ob,
    const float* __restrict__ aw, const float* __restrict__ ab,
    const float* __restrict__ outw,
    unsigned short* __restrict__ Wcat, unsigned short* __restrict__ Wo,
    float* __restrict__ bcat)
{
    int i = blockIdx.x * 256 + threadIdx.x;
    if (i < NPAD * E) {
        int n = i >> 8, k = i & 255;
        float w = 0.f;
        if      (n < 256) w = vw[n * E + k];
        else if (n < 320) w = ow[(n - 256) * E + k];
        else if (n < 352) w = aw[(n - 320) * E + k];
        Wcat[i] = f2b(w);
    } else {
        int j = i - NPAD * E;
        if (j < E * E) Wo[j] = f2b(outw[j]);
    }
    if (i < NPAD) {
        float bv = 0.f;
        if      (i < 256) bv = vb[i];
        else if (i < 320) bv = ob[i - 256];
        else if (i < 352) bv = ab[i - 320];
        bcat[i] = bv;
    }
}

// ---------------------------------------------------------------------------
// GEMM1 (projection), whole-K staging: 128 rows x 128 cols, K=256 all in LDS.
// One staging burst (A: fp32->bf16->ds_write, B: gload_lds), ONE barrier,
// then 64 MFMAs/wave with zero further syncs. 8 waves = 2m x 4n, wave tile
// 64x32 (4x2 frags). Grid (256, 3). LDS = 64KB A + 64KB B = 128KB.
// Granule layout (both): g = chunk*128 + row (16B granules, chunk = K/8).
// Epilogue scatter: col<256 -> Vt image layout; 256..351 -> Mt meta.
// ---------------------------------------------------------------------------
__global__ __launch_bounds__(512) void gemm_proj(
    const float* __restrict__ Aq,
    const unsigned short* __restrict__ W,
    const float* __restrict__ bias,
    unsigned short* __restrict__ Vt,
    unsigned short* __restrict__ Mt)
{
    __shared__ __align__(16) unsigned short ldsA[32768];  // 64KB
    __shared__ __align__(16) unsigned short ldsB[32768];  // 64KB

    const int tid  = threadIdx.x;
    const int lane = tid & 63;
    const int wave = tid >> 6;      // 0..7
    const int wm   = wave >> 2;     // 0..1 : 64-row halves
    const int wn   = wave & 3;      // 0..3 : 32-col quarters
    const int bm = blockIdx.x * 128;
    const int bn = blockIdx.y * 128;
    const int lrow = lane & 15, lchunk = lane >> 4;

    // B: 4096 granules via global->LDS (dest = wave-uniform + lane*16)
#pragma unroll
    for (int it = 0; it < 8; ++it) {
        int g = it * 512 + tid;
        int row = g & 127, chunk = g >> 7;
        gload16(W + (size_t)(bn + row) * 256 + chunk * 8, &ldsB[(size_t)g * 8]);
    }
    // A: 4096 granules, fp32 load + convert + ds_write
#pragma unroll
    for (int it = 0; it < 8; ++it) {
        int g = it * 512 + tid;
        int row = g & 127, chunk = g >> 7;
        const float* ap = Aq + (size_t)(bm + row) * 256 + chunk * 8;
        float4 f0 = *(const float4*)(ap + 0);
        float4 f1 = *(const float4*)(ap + 4);
        u16x8 o;
        o[0]=f2b(f0.x); o[1]=f2b(f0.y); o[2]=f2b(f0.z); o[3]=f2b(f0.w);
        o[4]=f2b(f1.x); o[5]=f2b(f1.y); o[6]=f2b(f1.z); o[7]=f2b(f1.w);
        *(u16x8*)&ldsA[(size_t)g * 8] = o;
    }
    __syncthreads();

    f32x4 acc[4][2] = {};
#pragma unroll
    for (int kk = 0; kk < 8; ++kk) {
        const int cb = (kk * 4 + lchunk) * 128;
        bf16x8 af[4], bfr[2];
#pragma unroll
        for (int m = 0; m < 4; ++m)
            af[m] = *(const bf16x8*)&ldsA[(size_t)(cb + wm * 64 + m * 16 + lrow) * 8];
#pragma unroll
        for (int n = 0; n < 2; ++n)
            bfr[n] = *(const bf16x8*)&ldsB[(size_t)(cb + wn * 32 + n * 16 + lrow) * 8];
#pragma unroll
        for (int m = 0; m < 4; ++m)
#pragma unroll
            for (int n = 0; n < 2; ++n)
                acc[m][n] = __builtin_amdgcn_mfma_f32_16x16x32_bf16(
                    af[m], bfr[n], acc[m][n], 0, 0, 0);
    }

    const int orow0 = (lane >> 4) * 4;
    const int ocol  = lane & 15;
#pragma unroll
    for (int n = 0; n < 2; ++n) {
        int colg = bn + wn * 32 + n * 16 + ocol;
        if (colg >= 352) continue;
        float bv = bias[colg];
#pragma unroll
        for (int m = 0; m < 4; ++m) {
#pragma unroll
            for (int r = 0; r < 4; ++r) {
                int rowg = bm + wm * 64 + m * 16 + orow0 + r;
                unsigned short v = f2b(acc[m][n][r] + bv);
                if (colg < 256) {
                    int b = rowg >> 12, q = rowg & 4095;
                    int h = colg >> 5, ch = colg & 31;
                    Vt[((size_t)(((b << 3) + h) << 12) + q) * 32 + ch] = v;
                } else if (colg < 320) {
                    Mt[(size_t)rowg * MSTR + (colg - 256)] = v;
                } else {
                    Mt[(size_t)rowg * MSTR + 64 + (colg - 320)] = v;
                }
            }
        }
    }
}

// ---------------------------------------------------------------------------
// Sampling: thread per (t, h, 8-ch group); 4096 blocks, XCD-swizzled so each
// XCD's L2 holds one batch image (2 MB). Branchless: clamped indices +
// validity-zeroed weights.
// ---------------------------------------------------------------------------
__global__ __launch_bounds__(256) void sample_kernel(
    const unsigned short* __restrict__ Vt,
    const unsigned short* __restrict__ Mt,
    unsigned short* __restrict__ S)
{
    const int blk = ((blockIdx.x & 7) << 9) + (blockIdx.x >> 3);  // 4096 = 8*512
    const int gid = blk * 256 + threadIdx.x;
    const int d0 = gid & 3;
    const int h  = (gid >> 2) & 7;
    const int t  = gid >> 5;
    const int b  = t >> 12;
    const int q  = t & 4095;

    const float refx = (float)(q & 63) * (64.0f / 63.0f);
    const float refy = (float)(q >> 6) * (64.0f / 63.0f);

    const unsigned short* __restrict__ mrow = Mt + (size_t)t * MSTR;
    u16x8  offv = *(const u16x8*)&mrow[h * 8];
    ushort4 lg  = *(const ushort4*)&mrow[64 + h * 4];

    float l0 = b2f(lg.x), l1 = b2f(lg.y), l2 = b2f(lg.z), l3 = b2f(lg.w);
    float m = fmaxf(fmaxf(l0, l1), fmaxf(l2, l3));
    float e0 = __expf(l0 - m), e1 = __expf(l1 - m);
    float e2 = __expf(l2 - m), e3 = __expf(l3 - m);
    float inv = 1.0f / (e0 + e1 + e2 + e3);
    float at[4] = {e0 * inv, e1 * inv, e2 * inv, e3 * inv};

    const unsigned short* __restrict__ vbase =
        Vt + ((size_t)(((b << 3) + h) << 12)) * 32 + d0 * 8;

    float acc[8] = {};
#pragma unroll
    for (int p = 0; p < NP; ++p) {
        float ox = b2f(offv[2 * p]);
        float oy = b2f(offv[2 * p + 1]);
        float px = refx + ox - 0.5f;
        float py = refy + oy - 0.5f;
        float fx = floorf(px), fy = floorf(py);
        int x0 = (int)fx, y0 = (int)fy;
        float wx = px - fx, wy = py - fy;
        float a = at[p];

        int x1 = x0 + 1, y1 = y0 + 1;
        float vx0 = (x0 >= 0 && x0 < GW) ? 1.f : 0.f;
        float vx1 = (x1 >= 0 && x1 < GW) ? 1.f : 0.f;
        float vy0 = (y0 >= 0 && y0 < GH) ? 1.f : 0.f;
        float vy1 = (y1 >= 0 && y1 < GH) ? 1.f : 0.f;

        float w00 = (1.f - wx) * (1.f - wy) * a * vx0 * vy0;
        float w10 = wx * (1.f - wy) * a * vx1 * vy0;
        float w01 = (1.f - wx) * wy * a * vx0 * vy1;
        float w11 = wx * wy * a * vx1 * vy1;

        int x0c = min(max(x0, 0), GW - 1), x1c = min(max(x1, 0), GW - 1);
        int y0c = min(max(y0, 0), GH - 1), y1c = min(max(y1, 0), GH - 1);

        u16x8 g00 = *(const u16x8*)&vbase[(size_t)(y0c * GW + x0c) * 32];
        u16x8 g10 = *(const u16x8*)&vbase[(size_t)(y0c * GW + x1c) * 32];
        u16x8 g01 = *(const u16x8*)&vbase[(size_t)(y1c * GW + x0c) * 32];
        u16x8 g11 = *(const u16x8*)&vbase[(size_t)(y1c * GW + x1c) * 32];
#pragma unroll
        for (int j = 0; j < 8; ++j)
            acc[j] += w00 * b2f(g00[j]) + w10 * b2f(g10[j])
                    + w01 * b2f(g01[j]) + w11 * b2f(g11[j]);
    }

    u16x8 o;
#pragma unroll
    for (int j = 0; j < 8; ++j) o[j] = f2b(acc[j]);
    *(u16x8*)&S[(size_t)t * E + h * HD + d0 * 8] = o;
}

// ---------------------------------------------------------------------------
// GEMM2 (output projection), whole-K staging like gemm_proj.
// S (T x 256 bf16) @ Wo^T + out_b + 2*query; fp32 out. Grid (256, 2).
// ---------------------------------------------------------------------------
__global__ __launch_bounds__(512) void gemm_out(
    const unsigned short* __restrict__ A,
    const unsigned short* __restrict__ W,
    const float* __restrict__ bias,
    const float* __restrict__ resid,
    float* __restrict__ Out)
{
    __shared__ __align__(16) unsigned short ldsA[32768];  // 64KB
    __shared__ __align__(16) unsigned short ldsB[32768];  // 64KB

    const int tid  = threadIdx.x;
    const int lane = tid & 63;
    const int wave = tid >> 6;
    const int wm   = wave >> 2;
    const int wn   = wave & 3;
    const int bm = blockIdx.x * 128;
    const int bn = blockIdx.y * 128;
    const int lrow = lane & 15, lchunk = lane >> 4;

#pragma unroll
    for (int it = 0; it < 8; ++it) {
        int g = it * 512 + tid;
        int row = g & 127, chunk = g >> 7;
        gload16(A + (size_t)(bm + row) * 256 + chunk * 8, &ldsA[(size_t)g * 8]);
        gload16(W + (size_t)(bn + row) * 256 + chunk * 8, &ldsB[(size_t)g * 8]);
    }
    __syncthreads();

    f32x4 acc[4][2] = {};
#pragma unroll
    for (int kk = 0; kk < 8; ++kk) {
        const int cb = (kk * 4 + lchunk) * 128;
        bf16x8 af[4], bfr[2];
#pragma unroll
        for (int m = 0; m < 4; ++m)
            af[m] = *(const bf16x8*)&ldsA[(size_t)(cb + wm * 64 + m * 16 + lrow) * 8];
#pragma unroll
        for (int n = 0; n < 2; ++n)
            bfr[n] = *(const bf16x8*)&ldsB[(size_t)(cb + wn * 32 + n * 16 + lrow) * 8];
#pragma unroll
        for (int m = 0; m < 4; ++m)
#pragma unroll
            for (int n = 0; n < 2; ++n)
                acc[m][n] = __builtin_amdgcn_mfma_f32_16x16x32_bf16(
                    af[m], bfr[n], acc[m][n], 0, 0, 0);
    }

    const int orow0 = (lane >> 4) * 4;
    const int ocol  = lane & 15;
#pragma unroll
    for (int n = 0; n < 2; ++n) {
        int colg = bn + wn * 32 + n * 16 + ocol;
        float bv = bias[colg];
#pragma unroll
        for (int m = 0; m < 4; ++m) {
#pragma unroll
            for (int r = 0; r < 4; ++r) {
                int rowg = bm + wm * 64 + m * 16 + orow0 + r;
                Out[(size_t)rowg * 256 + colg] =
                    acc[m][n][r] + bv + 2.0f * resid[(size_t)rowg * 256 + colg];
            }
        }
    }
}

// ---------------------------------------------------------------------------
extern "C" void kernel_launch(void* const* d_in, const int* in_sizes, int n_in,
                              void* d_out, int out_size, void* d_ws, size_t ws_size,
                              hipStream_t stream)
{
    const float* query   = (const float*)d_in[0];
    const float* value_w = (const float*)d_in[1];
    const float* value_b = (const float*)d_in[2];
    const float* off_w   = (const float*)d_in[3];
    const float* off_b   = (const float*)d_in[4];
    const float* attn_w  = (const float*)d_in[5];
    const float* attn_b  = (const float*)d_in[6];
    const float* out_w   = (const float*)d_in[7];
    const float* out_b   = (const float*)d_in[8];

    char* w = (char*)d_ws;
    unsigned short* Vt   = (unsigned short*)w;  w += (size_t)T * E * 2;      // 16 MB
    unsigned short* Mt   = (unsigned short*)w;  w += (size_t)T * MSTR * 2;   // 6 MB
    unsigned short* S    = (unsigned short*)w;  w += (size_t)T * E * 2;      // 16 MB
    unsigned short* Wcat = (unsigned short*)w;  w += (size_t)NPAD * E * 2;
    unsigned short* Wo   = (unsigned short*)w;  w += (size_t)E * E * 2;
    float*          bcat = (float*)w;

    prep_weights<<<(NPAD * E + E * E + 255) / 256, 256, 0, stream>>>(
        value_w, value_b, off_w, off_b, attn_w, attn_b, out_w, Wcat, Wo, bcat);

    dim3 g1(T / 128, 3);
    gemm_proj<<<g1, 512, 0, stream>>>(query, Wcat, bcat, Vt, Mt);

    sample_kernel<<<T * 32 / 256, 256, 0, stream>>>(Vt, Mt, S);

    dim3 g2(T / 128, 2);
    gemm_out<<<g2, 512, 0, stream>>>(S, Wo, out_b, query, (float*)d_out);
}

// Round 7
// 81.754 us; speedup vs baseline: 1.3170x; 1.0525x over previous
//
#include <hip/hip_runtime.h>
#include <hip/hip_bf16.h>
#include <math.h>

// Problem constants
#define BS 8
#define NQ 4096
#define E  256
#define NH 8
#define NP 4
#define HD 32
#define GW 64
#define GH 64
#define T  (BS * NQ)     // 32768
#define NPAD 384
#define MSTR 96          // meta row: 64 offsets + 32 logits (bf16)

typedef __attribute__((ext_vector_type(8))) short bf16x8;
typedef __attribute__((ext_vector_type(4))) float f32x4;
typedef __attribute__((ext_vector_type(8))) unsigned short u16x8;

__device__ __forceinline__ float b2f(unsigned short u) {
    union { unsigned int i; float f; } x; x.i = ((unsigned int)u) << 16; return x.f;
}
__device__ __forceinline__ unsigned short f2b(float f) {
    __hip_bfloat16 h = __float2bfloat16(f);
    return *reinterpret_cast<unsigned short*>(&h);
}
__device__ __forceinline__ void gload16(const void* g, void* l) {
    __builtin_amdgcn_global_load_lds(
        (__attribute__((address_space(1))) void*)g,
        (__attribute__((address_space(3))) void*)l, 16, 0, 0);
}

// ---------------------------------------------------------------------------
// prep: Wcat (NPAD x 256 bf16), Wo (256x256 bf16), bcat (fp32 NPAD)
// ---------------------------------------------------------------------------
__global__ __launch_bounds__(256) void prep_weights(
    const float* __restrict__ vw, const float* __restrict__ vb,
    const float* __restrict__ ow, const float* __restrict__ ob,
    const float* __restrict__ aw, const float* __restrict__ ab,
    const float* __restrict__ outw,
    unsigned short* __restrict__ Wcat, unsigned short* __restrict__ Wo,
    float* __restrict__ bcat)
{
    int i = blockIdx.x * 256 + threadIdx.x;
    if (i < NPAD * E) {
        int n = i >> 8, k = i & 255;
        float w = 0.f;
        if      (n < 256) w = vw[n * E + k];
        else if (n < 320) w = ow[(n - 256) * E + k];
        else if (n < 352) w = aw[(n - 320) * E + k];
        Wcat[i] = f2b(w);
    } else {
        int j = i - NPAD * E;
        if (j < E * E) Wo[j] = f2b(outw[j]);
    }
    if (i < NPAD) {
        float bv = 0.f;
        if      (i < 256) bv = vb[i];
        else if (i < 320) bv = ob[i - 256];
        else if (i < 352) bv = aw ? ab[i - 320] : 0.f;
        bcat[i] = bv;
    }
}

// ---------------------------------------------------------------------------
// GEMM1 (projection): 128x128 tile, BK=64, 4 K-steps, 32KB LDS -> 3-5
// blocks/CU for cross-block overlap of staging drains. 4 waves (2x2),
// wave tile 64x64, 32 MFMA/wave per K-step. A: fp32 -> bf16 regs -> LDS.
// B: global_load_lds. Granules [chunk 0..7][row 0..127] (chunk = local k/8).
// Epilogue scatter: col<256 -> Vt image layout; 256..351 -> Mt meta.
// ---------------------------------------------------------------------------
__global__ __launch_bounds__(256) void gemm_proj(
    const float* __restrict__ Aq,
    const unsigned short* __restrict__ W,
    const float* __restrict__ bias,
    unsigned short* __restrict__ Vt,
    unsigned short* __restrict__ Mt)
{
    __shared__ __align__(16) unsigned short ldsA[8192];  // 16KB, 1024 granules
    __shared__ __align__(16) unsigned short ldsB[8192];  // 16KB

    const int tid  = threadIdx.x;
    const int lane = tid & 63;
    const int wave = tid >> 6;
    const int wm = wave >> 1, wn = wave & 1;
    const int bm = blockIdx.x * 128;
    const int bn = blockIdx.y * 128;
    const int lrow = lane & 15, lchunk = lane >> 4;

    f32x4 acc[4][4] = {};

    for (int k0 = 0; k0 < 256; k0 += 64) {
        // B: 1024 granules via global->LDS (dest = wave-uniform + lane*16B)
#pragma unroll
        for (int it = 0; it < 4; ++it) {
            int g = it * 256 + wave * 64 + lane;
            int row = g & 127, chunk = g >> 7;
            gload16(W + (size_t)(bn + row) * 256 + k0 + chunk * 8,
                    &ldsB[(size_t)g * 8]);
        }
        // A: 1024 granules, fp32 load + convert + ds_write
#pragma unroll
        for (int it = 0; it < 4; ++it) {
            int g = it * 256 + tid;
            int row = g & 127, chunk = g >> 7;
            const float* ap = Aq + (size_t)(bm + row) * 256 + k0 + chunk * 8;
            float4 f0 = *(const float4*)(ap + 0);
            float4 f1 = *(const float4*)(ap + 4);
            u16x8 o;
            o[0]=f2b(f0.x); o[1]=f2b(f0.y); o[2]=f2b(f0.z); o[3]=f2b(f0.w);
            o[4]=f2b(f1.x); o[5]=f2b(f1.y); o[6]=f2b(f1.z); o[7]=f2b(f1.w);
            *(u16x8*)&ldsA[(size_t)g * 8] = o;
        }
        __syncthreads();

#pragma unroll
        for (int ks = 0; ks < 2; ++ks) {
            const int cb = (ks * 4 + lchunk) * 128;
            bf16x8 af[4], bfr[4];
#pragma unroll
            for (int m = 0; m < 4; ++m)
                af[m] = *(const bf16x8*)&ldsA[(size_t)(cb + wm * 64 + m * 16 + lrow) * 8];
#pragma unroll
            for (int n = 0; n < 4; ++n)
                bfr[n] = *(const bf16x8*)&ldsB[(size_t)(cb + wn * 64 + n * 16 + lrow) * 8];
#pragma unroll
            for (int m = 0; m < 4; ++m)
#pragma unroll
                for (int n = 0; n < 4; ++n)
                    acc[m][n] = __builtin_amdgcn_mfma_f32_16x16x32_bf16(
                        af[m], bfr[n], acc[m][n], 0, 0, 0);
        }
        __syncthreads();
    }

    const int orow0 = (lane >> 4) * 4;
    const int ocol  = lane & 15;
#pragma unroll
    for (int n = 0; n < 4; ++n) {
        int colg = bn + wn * 64 + n * 16 + ocol;
        if (colg >= 352) continue;
        float bv = bias[colg];
#pragma unroll
        for (int m = 0; m < 4; ++m) {
#pragma unroll
            for (int r = 0; r < 4; ++r) {
                int rowg = bm + wm * 64 + m * 16 + orow0 + r;
                unsigned short v = f2b(acc[m][n][r] + bv);
                if (colg < 256) {
                    int b = rowg >> 12, q = rowg & 4095;
                    int h = colg >> 5, ch = colg & 31;
                    Vt[((size_t)(((b << 3) + h) << 12) + q) * 32 + ch] = v;
                } else if (colg < 320) {
                    Mt[(size_t)rowg * MSTR + (colg - 256)] = v;
                } else {
                    Mt[(size_t)rowg * MSTR + 64 + (colg - 320)] = v;
                }
            }
        }
    }
}

// ---------------------------------------------------------------------------
// Sampling: thread per (t, h, 8-ch group); 4096 blocks, XCD-swizzled so each
// XCD's L2 holds one batch image (2 MB). Branchless clamped+masked bilinear.
// ---------------------------------------------------------------------------
__global__ __launch_bounds__(256) void sample_kernel(
    const unsigned short* __restrict__ Vt,
    const unsigned short* __restrict__ Mt,
    unsigned short* __restrict__ S)
{
    const int blk = ((blockIdx.x & 7) << 9) + (blockIdx.x >> 3);  // 4096 = 8*512
    const int gid = blk * 256 + threadIdx.x;
    const int d0 = gid & 3;
    const int h  = (gid >> 2) & 7;
    const int t  = gid >> 5;
    const int b  = t >> 12;
    const int q  = t & 4095;

    const float refx = (float)(q & 63) * (64.0f / 63.0f);
    const float refy = (float)(q >> 6) * (64.0f / 63.0f);

    const unsigned short* __restrict__ mrow = Mt + (size_t)t * MSTR;
    u16x8  offv = *(const u16x8*)&mrow[h * 8];
    ushort4 lg  = *(const ushort4*)&mrow[64 + h * 4];

    float l0 = b2f(lg.x), l1 = b2f(lg.y), l2 = b2f(lg.z), l3 = b2f(lg.w);
    float m = fmaxf(fmaxf(l0, l1), fmaxf(l2, l3));
    float e0 = __expf(l0 - m), e1 = __expf(l1 - m);
    float e2 = __expf(l2 - m), e3 = __expf(l3 - m);
    float inv = 1.0f / (e0 + e1 + e2 + e3);
    float at[4] = {e0 * inv, e1 * inv, e2 * inv, e3 * inv};

    const unsigned short* __restrict__ vbase =
        Vt + ((size_t)(((b << 3) + h) << 12)) * 32 + d0 * 8;

    float acc[8] = {};
#pragma unroll
    for (int p = 0; p < NP; ++p) {
        float ox = b2f(offv[2 * p]);
        float oy = b2f(offv[2 * p + 1]);
        float px = refx + ox - 0.5f;
        float py = refy + oy - 0.5f;
        float fx = floorf(px), fy = floorf(py);
        int x0 = (int)fx, y0 = (int)fy;
        float wx = px - fx, wy = py - fy;
        float a = at[p];

        int x1 = x0 + 1, y1 = y0 + 1;
        float vx0 = (x0 >= 0 && x0 < GW) ? 1.f : 0.f;
        float vx1 = (x1 >= 0 && x1 < GW) ? 1.f : 0.f;
        float vy0 = (y0 >= 0 && y0 < GH) ? 1.f : 0.f;
        float vy1 = (y1 >= 0 && y1 < GH) ? 1.f : 0.f;

        float w00 = (1.f - wx) * (1.f - wy) * a * vx0 * vy0;
        float w10 = wx * (1.f - wy) * a * vx1 * vy0;
        float w01 = (1.f - wx) * wy * a * vx0 * vy1;
        float w11 = wx * wy * a * vx1 * vy1;

        int x0c = min(max(x0, 0), GW - 1), x1c = min(max(x1, 0), GW - 1);
        int y0c = min(max(y0, 0), GH - 1), y1c = min(max(y1, 0), GH - 1);

        u16x8 g00 = *(const u16x8*)&vbase[(size_t)(y0c * GW + x0c) * 32];
        u16x8 g10 = *(const u16x8*)&vbase[(size_t)(y0c * GW + x1c) * 32];
        u16x8 g01 = *(const u16x8*)&vbase[(size_t)(y1c * GW + x0c) * 32];
        u16x8 g11 = *(const u16x8*)&vbase[(size_t)(y1c * GW + x1c) * 32];
#pragma unroll
        for (int j = 0; j < 8; ++j)
            acc[j] += w00 * b2f(g00[j]) + w10 * b2f(g10[j])
                    + w01 * b2f(g01[j]) + w11 * b2f(g11[j]);
    }

    u16x8 o;
#pragma unroll
    for (int j = 0; j < 8; ++j) o[j] = f2b(acc[j]);
    *(u16x8*)&S[(size_t)t * E + h * HD + d0 * 8] = o;
}

// ---------------------------------------------------------------------------
// GEMM2 (output projection): 128x128 tile, BK=64, both operands gload_lds.
// S (T x 256 bf16) @ Wo^T + out_b + 2*query; fp32 out. Grid (256, 2).
// ---------------------------------------------------------------------------
__global__ __launch_bounds__(256) void gemm_out(
    const unsigned short* __restrict__ A,
    const unsigned short* __restrict__ W,
    const float* __restrict__ bias,
    const float* __restrict__ resid,
    float* __restrict__ Out)
{
    __shared__ __align__(16) unsigned short ldsA[8192];
    __shared__ __align__(16) unsigned short ldsB[8192];

    const int tid  = threadIdx.x;
    const int lane = tid & 63;
    const int wave = tid >> 6;
    const int wm = wave >> 1, wn = wave & 1;
    const int bm = blockIdx.x * 128;
    const int bn = blockIdx.y * 128;
    const int lrow = lane & 15, lchunk = lane >> 4;

    f32x4 acc[4][4] = {};

    for (int k0 = 0; k0 < 256; k0 += 64) {
#pragma unroll
        for (int it = 0; it < 4; ++it) {
            int g = it * 256 + wave * 64 + lane;
            int row = g & 127, chunk = g >> 7;
            gload16(A + (size_t)(bm + row) * 256 + k0 + chunk * 8,
                    &ldsA[(size_t)g * 8]);
            gload16(W + (size_t)(bn + row) * 256 + k0 + chunk * 8,
                    &ldsB[(size_t)g * 8]);
        }
        __syncthreads();

#pragma unroll
        for (int ks = 0; ks < 2; ++ks) {
            const int cb = (ks * 4 + lchunk) * 128;
            bf16x8 af[4], bfr[4];
#pragma unroll
            for (int m = 0; m < 4; ++m)
                af[m] = *(const bf16x8*)&ldsA[(size_t)(cb + wm * 64 + m * 16 + lrow) * 8];
#pragma unroll
            for (int n = 0; n < 4; ++n)
                bfr[n] = *(const bf16x8*)&ldsB[(size_t)(cb + wn * 64 + n * 16 + lrow) * 8];
#pragma unroll
            for (int m = 0; m < 4; ++m)
#pragma unroll
                for (int n = 0; n < 4; ++n)
                    acc[m][n] = __builtin_amdgcn_mfma_f32_16x16x32_bf16(
                        af[m], bfr[n], acc[m][n], 0, 0, 0);
        }
        __syncthreads();
    }

    const int orow0 = (lane >> 4) * 4;
    const int ocol  = lane & 15;
#pragma unroll
    for (int m = 0; m < 4; ++m) {
#pragma unroll
        for (int n = 0; n < 4; ++n) {
            int colg = bn + wn * 64 + n * 16 + ocol;
            float bv = bias[colg];
#pragma unroll
            for (int r = 0; r < 4; ++r) {
                int rowg = bm + wm * 64 + m * 16 + orow0 + r;
                Out[(size_t)rowg * 256 + colg] =
                    acc[m][n][r] + bv + 2.0f * resid[(size_t)rowg * 256 + colg];
            }
        }
    }
}

// ---------------------------------------------------------------------------
extern "C" void kernel_launch(void* const* d_in, const int* in_sizes, int n_in,
                              void* d_out, int out_size, void* d_ws, size_t ws_size,
                              hipStream_t stream)
{
    const float* query   = (const float*)d_in[0];
    const float* value_w = (const float*)d_in[1];
    const float* value_b = (const float*)d_in[2];
    const float* off_w   = (const float*)d_in[3];
    const float* off_b   = (const float*)d_in[4];
    const float* attn_w  = (const float*)d_in[5];
    const float* attn_b  = (const float*)d_in[6];
    const float* out_w   = (const float*)d_in[7];
    const float* out_b   = (const float*)d_in[8];

    char* w = (char*)d_ws;
    unsigned short* Vt   = (unsigned short*)w;  w += (size_t)T * E * 2;      // 16 MB
    unsigned short* Mt   = (unsigned short*)w;  w += (size_t)T * MSTR * 2;   // 6 MB
    unsigned short* S    = (unsigned short*)w;  w += (size_t)T * E * 2;      // 16 MB
    unsigned short* Wcat = (unsigned short*)w;  w += (size_t)NPAD * E * 2;
    unsigned short* Wo   = (unsigned short*)w;  w += (size_t)E * E * 2;
    float*          bcat = (float*)w;

    prep_weights<<<(NPAD * E + E * E + 255) / 256, 256, 0, stream>>>(
        value_w, value_b, off_w, off_b, attn_w, attn_b, out_w, Wcat, Wo, bcat);

    dim3 g1(T / 128, 3);
    gemm_proj<<<g1, 256, 0, stream>>>(query, Wcat, bcat, Vt, Mt);

    sample_kernel<<<T * 32 / 256, 256, 0, stream>>>(Vt, Mt, S);

    dim3 g2(T / 128, 2);
    gemm_out<<<g2, 256, 0, stream>>>(S, Wo, out_b, query, (float*)d_out);
}

// Round 8
// 55.142 us; speedup vs baseline: 1.9525x; 1.4826x over previous
//
#include <hip/hip_runtime.h>
#include <hip/hip_bf16.h>
#include <math.h>

// Problem constants
#define BS 8
#define NQ 4096
#define E  256
#define NH 8
#define NP 4
#define HD 32
#define GW 64
#define GH 64
#define T  (BS * NQ)     // 32768
#define NPAD 384
#define MSTR 96          // meta row: 64 offsets + 32 logits (bf16)

typedef __attribute__((ext_vector_type(8))) short bf16x8;
typedef __attribute__((ext_vector_type(4))) float f32x4;
typedef __attribute__((ext_vector_type(8))) unsigned short u16x8;

__device__ __forceinline__ float b2f(unsigned short u) {
    union { unsigned int i; float f; } x; x.i = ((unsigned int)u) << 16; return x.f;
}
__device__ __forceinline__ unsigned short f2b(float f) {
    __hip_bfloat16 h = __float2bfloat16(f);
    return *reinterpret_cast<unsigned short*>(&h);
}
__device__ __forceinline__ void gload16(const void* g, void* l) {
    __builtin_amdgcn_global_load_lds(
        (__attribute__((address_space(1))) void*)g,
        (__attribute__((address_space(3))) void*)l, 16, 0, 0);
}

// Swizzled granule layout for all GEMM operand tiles:
//   tile = [NR rows][8 chunks] of 16B granules (chunk = 8 k-elements of BK=64)
//   granule index g (lane-linear dest) = row*8 + stored_chunk,
//   stored_chunk = logical_chunk ^ (row & 7).
// Staging: lane l fetches global (row=g>>3, c=(g&7)^(row&7)) -> 8 consecutive
// lanes read one contiguous (permuted) 128B row => fully coalesced.
// Frag read: granule = row*8 + (C ^ (row&7)) => 16 lanes spread over all 8
// bank-quads (2-way = free).

// ---------------------------------------------------------------------------
// prep: Wcat (NPAD x 256 bf16), Wo (256x256 bf16), bcat (fp32 NPAD)
// ---------------------------------------------------------------------------
__global__ __launch_bounds__(256) void prep_weights(
    const float* __restrict__ vw, const float* __restrict__ vb,
    const float* __restrict__ ow, const float* __restrict__ ob,
    const float* __restrict__ aw, const float* __restrict__ ab,
    const float* __restrict__ outw,
    unsigned short* __restrict__ Wcat, unsigned short* __restrict__ Wo,
    float* __restrict__ bcat)
{
    int i = blockIdx.x * 256 + threadIdx.x;
    if (i < NPAD * E) {
        int n = i >> 8, k = i & 255;
        float w = 0.f;
        if      (n < 256) w = vw[n * E + k];
        else if (n < 320) w = ow[(n - 256) * E + k];
        else if (n < 352) w = aw[(n - 320) * E + k];
        Wcat[i] = f2b(w);
    } else {
        int j = i - NPAD * E;
        if (j < E * E) Wo[j] = f2b(outw[j]);
    }
    if (i < NPAD) {
        float bv = 0.f;
        if      (i < 256) bv = vb[i];
        else if (i < 320) bv = ob[i - 256];
        else if (i < 352) bv = ab[i - 320];
        bcat[i] = bv;
    }
}

// ---------------------------------------------------------------------------
// GEMM1 (projection): 64 rows x 384 cols per block -> query read ONCE.
// BK=64, 4 K-steps. 8 waves (2m x 4n), wave tile 32x96 (2x6 frags),
// 24 MFMA/wave/step. LDS: A 8KB + B 48KB = 56KB -> 2 blocks/CU, grid 512.
// A: fp32 -> bf16 regs -> conflict-free lane-linear ds_write.
// B: gload_lds, lane-linear dest, swizzle-permuted coalesced source.
// Epilogue scatter: col<256 -> Vt image layout; 256..351 -> Mt meta.
// ---------------------------------------------------------------------------
__global__ __launch_bounds__(512) void gemm_proj(
    const float* __restrict__ Aq,
    const unsigned short* __restrict__ W,
    const float* __restrict__ bias,
    unsigned short* __restrict__ Vt,
    unsigned short* __restrict__ Mt)
{
    __shared__ __align__(16) unsigned short ldsA[4096];   // 512 granules
    __shared__ __align__(16) unsigned short ldsB[24576];  // 3072 granules

    const int tid  = threadIdx.x;
    const int lane = tid & 63;
    const int wave = tid >> 6;      // 0..7
    const int wm   = wave >> 2;     // 0..1 : 32-row halves
    const int wn   = wave & 3;      // 0..3 : 96-col quarters
    const int bm   = blockIdx.x * 64;
    const int lrow = lane & 15, lchunk = lane >> 4;

    f32x4 acc[2][6] = {};

    for (int k0 = 0; k0 < 256; k0 += 64) {
        // B: 3072 granules, 6 per thread, lane-linear dest
#pragma unroll
        for (int p = 0; p < 6; ++p) {
            int g = p * 512 + tid;
            int row = g >> 3;
            int c = (g & 7) ^ (row & 7);
            gload16(W + (size_t)row * 256 + k0 + c * 8, &ldsB[(size_t)g * 8]);
        }
        // A: 512 granules, 1 per thread; 8 consecutive lanes cover one row
        {
            int row = tid >> 3;
            int c = (tid & 7) ^ (row & 7);
            const float* ap = Aq + (size_t)(bm + row) * 256 + k0 + c * 8;
            float4 f0 = *(const float4*)(ap + 0);
            float4 f1 = *(const float4*)(ap + 4);
            u16x8 o;
            o[0]=f2b(f0.x); o[1]=f2b(f0.y); o[2]=f2b(f0.z); o[3]=f2b(f0.w);
            o[4]=f2b(f1.x); o[5]=f2b(f1.y); o[6]=f2b(f1.z); o[7]=f2b(f1.w);
            *(u16x8*)&ldsA[(size_t)tid * 8] = o;
        }
        __syncthreads();

#pragma unroll
        for (int kk = 0; kk < 2; ++kk) {
            const int C = kk * 4 + lchunk;     // logical chunk 0..7
            bf16x8 af[2], bfr[6];
#pragma unroll
            for (int m = 0; m < 2; ++m) {
                int row = wm * 32 + m * 16 + lrow;
                af[m] = *(const bf16x8*)&ldsA[(size_t)(row * 8 + (C ^ (row & 7))) * 8];
            }
#pragma unroll
            for (int n = 0; n < 6; ++n) {
                int row = wn * 96 + n * 16 + lrow;
                bfr[n] = *(const bf16x8*)&ldsB[(size_t)(row * 8 + (C ^ (row & 7))) * 8];
            }
#pragma unroll
            for (int m = 0; m < 2; ++m)
#pragma unroll
                for (int n = 0; n < 6; ++n)
                    acc[m][n] = __builtin_amdgcn_mfma_f32_16x16x32_bf16(
                        af[m], bfr[n], acc[m][n], 0, 0, 0);
        }
        __syncthreads();
    }

    const int orow0 = (lane >> 4) * 4;
    const int ocol  = lane & 15;
#pragma unroll
    for (int n = 0; n < 6; ++n) {
        int colg = wn * 96 + n * 16 + ocol;
        if (colg >= 352) continue;
        float bv = bias[colg];
#pragma unroll
        for (int m = 0; m < 2; ++m) {
#pragma unroll
            for (int r = 0; r < 4; ++r) {
                int rowg = bm + wm * 32 + m * 16 + orow0 + r;
                unsigned short v = f2b(acc[m][n][r] + bv);
                if (colg < 256) {
                    int b = rowg >> 12, q = rowg & 4095;
                    int h = colg >> 5, ch = colg & 31;
                    Vt[((size_t)(((b << 3) + h) << 12) + q) * 32 + ch] = v;
                } else if (colg < 320) {
                    Mt[(size_t)rowg * MSTR + (colg - 256)] = v;
                } else {
                    Mt[(size_t)rowg * MSTR + 64 + (colg - 320)] = v;
                }
            }
        }
    }
}

// ---------------------------------------------------------------------------
// Sampling: thread per (t, h, 8-ch group); 4096 blocks, XCD-swizzled so each
// XCD's L2 holds one batch image (2 MB). Branchless clamped+masked bilinear.
// ---------------------------------------------------------------------------
__global__ __launch_bounds__(256) void sample_kernel(
    const unsigned short* __restrict__ Vt,
    const unsigned short* __restrict__ Mt,
    unsigned short* __restrict__ S)
{
    const int blk = ((blockIdx.x & 7) << 9) + (blockIdx.x >> 3);  // 4096 = 8*512
    const int gid = blk * 256 + threadIdx.x;
    const int d0 = gid & 3;
    const int h  = (gid >> 2) & 7;
    const int t  = gid >> 5;
    const int b  = t >> 12;
    const int q  = t & 4095;

    const float refx = (float)(q & 63) * (64.0f / 63.0f);
    const float refy = (float)(q >> 6) * (64.0f / 63.0f);

    const unsigned short* __restrict__ mrow = Mt + (size_t)t * MSTR;
    u16x8  offv = *(const u16x8*)&mrow[h * 8];
    ushort4 lg  = *(const ushort4*)&mrow[64 + h * 4];

    float l0 = b2f(lg.x), l1 = b2f(lg.y), l2 = b2f(lg.z), l3 = b2f(lg.w);
    float m = fmaxf(fmaxf(l0, l1), fmaxf(l2, l3));
    float e0 = __expf(l0 - m), e1 = __expf(l1 - m);
    float e2 = __expf(l2 - m), e3 = __expf(l3 - m);
    float inv = 1.0f / (e0 + e1 + e2 + e3);
    float at[4] = {e0 * inv, e1 * inv, e2 * inv, e3 * inv};

    const unsigned short* __restrict__ vbase =
        Vt + ((size_t)(((b << 3) + h) << 12)) * 32 + d0 * 8;

    float acc[8] = {};
#pragma unroll
    for (int p = 0; p < NP; ++p) {
        float ox = b2f(offv[2 * p]);
        float oy = b2f(offv[2 * p + 1]);
        float px = refx + ox - 0.5f;
        float py = refy + oy - 0.5f;
        float fx = floorf(px), fy = floorf(py);
        int x0 = (int)fx, y0 = (int)fy;
        float wx = px - fx, wy = py - fy;
        float a = at[p];

        int x1 = x0 + 1, y1 = y0 + 1;
        float vx0 = (x0 >= 0 && x0 < GW) ? 1.f : 0.f;
        float vx1 = (x1 >= 0 && x1 < GW) ? 1.f : 0.f;
        float vy0 = (y0 >= 0 && y0 < GH) ? 1.f : 0.f;
        float vy1 = (y1 >= 0 && y1 < GH) ? 1.f : 0.f;

        float w00 = (1.f - wx) * (1.f - wy) * a * vx0 * vy0;
        float w10 = wx * (1.f - wy) * a * vx1 * vy0;
        float w01 = (1.f - wx) * wy * a * vx0 * vy1;
        float w11 = wx * wy * a * vx1 * vy1;

        int x0c = min(max(x0, 0), GW - 1), x1c = min(max(x1, 0), GW - 1);
        int y0c = min(max(y0, 0), GH - 1), y1c = min(max(y1, 0), GH - 1);

        u16x8 g00 = *(const u16x8*)&vbase[(size_t)(y0c * GW + x0c) * 32];
        u16x8 g10 = *(const u16x8*)&vbase[(size_t)(y0c * GW + x1c) * 32];
        u16x8 g01 = *(const u16x8*)&vbase[(size_t)(y1c * GW + x0c) * 32];
        u16x8 g11 = *(const u16x8*)&vbase[(size_t)(y1c * GW + x1c) * 32];
#pragma unroll
        for (int j = 0; j < 8; ++j)
            acc[j] += w00 * b2f(g00[j]) + w10 * b2f(g10[j])
                    + w01 * b2f(g01[j]) + w11 * b2f(g11[j]);
    }

    u16x8 o;
#pragma unroll
    for (int j = 0; j < 8; ++j) o[j] = f2b(acc[j]);
    *(u16x8*)&S[(size_t)t * E + h * HD + d0 * 8] = o;
}

// ---------------------------------------------------------------------------
// GEMM2 (output projection): 64 rows x 256 cols per block -> S read ONCE.
// BK=64, 4 K-steps. 8 waves (2m x 4n), wave tile 32x64 (2x4 frags).
// LDS: A 8KB + B 32KB = 40KB -> 4 blocks/CU, grid 512. Both via gload_lds.
// Out = acc + bias + 2*resid (fp32).
// ---------------------------------------------------------------------------
__global__ __launch_bounds__(512) void gemm_out(
    const unsigned short* __restrict__ A,
    const unsigned short* __restrict__ W,
    const float* __restrict__ bias,
    const float* __restrict__ resid,
    float* __restrict__ Out)
{
    __shared__ __align__(16) unsigned short ldsA[4096];   // 512 granules
    __shared__ __align__(16) unsigned short ldsB[16384];  // 2048 granules

    const int tid  = threadIdx.x;
    const int lane = tid & 63;
    const int wave = tid >> 6;
    const int wm   = wave >> 2;
    const int wn   = wave & 3;
    const int bm   = blockIdx.x * 64;
    const int lrow = lane & 15, lchunk = lane >> 4;

    f32x4 acc[2][4] = {};

    for (int k0 = 0; k0 < 256; k0 += 64) {
        // A: 512 granules, 1 per thread
        {
            int row = tid >> 3;
            int c = (tid & 7) ^ (row & 7);
            gload16(A + (size_t)(bm + row) * 256 + k0 + c * 8,
                    &ldsA[(size_t)tid * 8]);
        }
        // B: 2048 granules, 4 per thread
#pragma unroll
        for (int p = 0; p < 4; ++p) {
            int g = p * 512 + tid;
            int row = g >> 3;
            int c = (g & 7) ^ (row & 7);
            gload16(W + (size_t)row * 256 + k0 + c * 8, &ldsB[(size_t)g * 8]);
        }
        __syncthreads();

#pragma unroll
        for (int kk = 0; kk < 2; ++kk) {
            const int C = kk * 4 + lchunk;
            bf16x8 af[2], bfr[4];
#pragma unroll
            for (int m = 0; m < 2; ++m) {
                int row = wm * 32 + m * 16 + lrow;
                af[m] = *(const bf16x8*)&ldsA[(size_t)(row * 8 + (C ^ (row & 7))) * 8];
            }
#pragma unroll
            for (int n = 0; n < 4; ++n) {
                int row = wn * 64 + n * 16 + lrow;
                bfr[n] = *(const bf16x8*)&ldsB[(size_t)(row * 8 + (C ^ (row & 7))) * 8];
            }
#pragma unroll
            for (int m = 0; m < 2; ++m)
#pragma unroll
                for (int n = 0; n < 4; ++n)
                    acc[m][n] = __builtin_amdgcn_mfma_f32_16x16x32_bf16(
                        af[m], bfr[n], acc[m][n], 0, 0, 0);
        }
        __syncthreads();
    }

    const int orow0 = (lane >> 4) * 4;
    const int ocol  = lane & 15;
#pragma unroll
    for (int m = 0; m < 2; ++m) {
#pragma unroll
        for (int n = 0; n < 4; ++n) {
            int colg = wn * 64 + n * 16 + ocol;
            float bv = bias[colg];
#pragma unroll
            for (int r = 0; r < 4; ++r) {
                int rowg = bm + wm * 32 + m * 16 + orow0 + r;
                Out[(size_t)rowg * 256 + colg] =
                    acc[m][n][r] + bv + 2.0f * resid[(size_t)rowg * 256 + colg];
            }
        }
    }
}

// ---------------------------------------------------------------------------
extern "C" void kernel_launch(void* const* d_in, const int* in_sizes, int n_in,
                              void* d_out, int out_size, void* d_ws, size_t ws_size,
                              hipStream_t stream)
{
    const float* query   = (const float*)d_in[0];
    const float* value_w = (const float*)d_in[1];
    const float* value_b = (const float*)d_in[2];
    const float* off_w   = (const float*)d_in[3];
    const float* off_b   = (const float*)d_in[4];
    const float* attn_w  = (const float*)d_in[5];
    const float* attn_b  = (const float*)d_in[6];
    const float* out_w   = (const float*)d_in[7];
    const float* out_b   = (const float*)d_in[8];

    char* w = (char*)d_ws;
    unsigned short* Vt   = (unsigned short*)w;  w += (size_t)T * E * 2;      // 16 MB
    unsigned short* Mt   = (unsigned short*)w;  w += (size_t)T * MSTR * 2;   // 6 MB
    unsigned short* S    = (unsigned short*)w;  w += (size_t)T * E * 2;      // 16 MB
    unsigned short* Wcat = (unsigned short*)w;  w += (size_t)NPAD * E * 2;
    unsigned short* Wo   = (unsigned short*)w;  w += (size_t)E * E * 2;
    float*          bcat = (float*)w;

    prep_weights<<<(NPAD * E + E * E + 255) / 256, 256, 0, stream>>>(
        value_w, value_b, off_w, off_b, attn_w, attn_b, out_w, Wcat, Wo, bcat);

    gemm_proj<<<T / 64, 512, 0, stream>>>(query, Wcat, bcat, Vt, Mt);

    sample_kernel<<<T * 32 / 256, 256, 0, stream>>>(Vt, Mt, S);

    gemm_out<<<T / 64, 512, 0, stream>>>(S, Wo, out_b, query, (float*)d_out);
}